// Round 10
// baseline (2855.451 us; speedup 1.0000x reference)
//
#include <hip/hip_runtime.h>

// ---------------------------------------------------------------------------
// TreeCaps forward, MI355X fp32 implementation.
// Fixed forest: per graph of 1024 nodes, node p's children are 4p+1..4p+4;
// nodes 0..255 are internal (updated each layer), 256..1023 are leaves.
// R4: occupancy attack -> WIN (523->476).  R7: zsweep atomics out -> 432.
// R9: multi-kernel reference 434us (front half measured 181us in R11).
// R10: fused back half + counter barrier: CORRECT but 2392us (RMW storm).
// R11: load-poll, RMW arrivals kept -> 2762us. Quantitative fit: 256
//      sequential cross-XCD ownership transfers on ONE line ~= 187us/barrier.
// R12: (this round) decentralized flag barrier, ZERO shared-line RMWs:
//   - arrival: release-store to per-block 64B-strided flag (parallel);
//   - block 0 aggregates with 255 concurrent acquire-loads, release-stores
//     a go word; other leaders acquire-poll go (read-sharing, no ownership);
//   - VTS barriers demoted to per-graph 8-block group barriers (VTS is
//     per-graph independent); 5 group + 8 global vs 13 global.
//   Fence bracketing identical to R10/R11 (twice verified absmax 0.0).
// ---------------------------------------------------------------------------

#define BG      32
#define NPG     1024
#define HH      128
#define NLAY    4
#define INT_PG  256
#define M_INT   8192      // BG*INT_PG
#define NN      32768     // BG*NPG
#define EPG     1023
#define DCC     16
#define NS      50
#define NBK     256       // back-half grid size (blocks)

// barrier memory layout (u32 indices): [0,4096) global flags (256 x 16),
// 4096+0..15 go line (GO_OFF=4096), [4112,8208) group flags (256 x 16),
// [8208,8720) per-graph go lines (32 x 16).
#define GO_OFF    4096
#define VFLAG_OFF 4112
#define VGO_OFF   8208
#define BAR_WORDS 8720

// ---- init: embed h0 (leaves to both bufs) + transpose Wjm -> WT -----------
__global__ void k_init(const int* __restrict__ tids, const int* __restrict__ kids,
                       const float* __restrict__ temb, const float* __restrict__ kemb,
                       float* __restrict__ hA, float* __restrict__ hB,
                       const float* __restrict__ Wjm, float* __restrict__ WT,
                       unsigned* __restrict__ barm) {
  __shared__ float w[3200];
  int tid = threadIdx.x;
  if (blockIdx.x < 4096) {                         // ---- embed part
    int idx = blockIdx.x * 256 + tid;              // NN*32
    int n = idx >> 5, c4 = idx & 31;
    float4 v;
    if (c4 < 16) v = *(const float4*)(temb + tids[n] * 64 + c4 * 4);
    else         v = *(const float4*)(kemb + kids[n] * 64 + (c4 - 16) * 4);
    *(float4*)(hA + n * 128 + c4 * 4) = v;
    if ((n & 1023) >= INT_PG)                      // leaves constant in both bufs
      *(float4*)(hB + n * 128 + c4 * 4) = v;
  } else {                                         // ---- transW part
    int n = blockIdx.x - 4096;
    if (n == 0)                                    // zero barrier flags
      for (int i = tid; i < BAR_WORDS; i += 256) barm[i] = 0;
    for (int i = tid; i < 3200; i += 256) w[i] = Wjm[n * 3200 + i];
    __syncthreads();
    for (int i = tid; i < 3200; i += 256) {
      int s = i >> 6, cm = i & 63;
      int cc = cm >> 2, m = cm & 3;
      WT[(s * 1024 + n) * 64 + cm] = w[(cc * NS + s) * 4 + m];
    }
  }
}

// --- fused gather+conv: new_h = relu(hl@Wl + hr@Wr + h@Wt + b) -------------
__global__ __launch_bounds__(256) void k_conv(
    const float* __restrict__ hp, float* __restrict__ hn,
    const int* __restrict__ src, const float* __restrict__ lw,
    const float* __restrict__ rw,
    const float* __restrict__ Wl, const float* __restrict__ Wr,
    const float* __restrict__ Wt, const float* __restrict__ bias,
    float* __restrict__ feat) {
  __shared__ float Ws[2][32][128];   // 32 KB
  __shared__ float AsT[2][32][20];   // 5 KB, padded
  __shared__ float hlS[16][128];     // 8 KB
  __shared__ float hrS[16][128];     // 8 KB
  int tid = threadIdx.x;
  int tx = tid & 31, ty = tid >> 5;
  int rowBase = blockIdx.x * 16;
  int g = rowBase >> 8, plBase = rowBase & 255;
  int nodeBase = g * NPG + plBase;

  #pragma unroll
  for (int t = 0; t < 2; ++t) {
    int it = t * 256 + tid;                  // 0..511
    int pw = it >> 5, c4 = it & 31;
    int pl = plBase + pw;
    float4 al = make_float4(0.f, 0.f, 0.f, 0.f);
    float4 ar = make_float4(0.f, 0.f, 0.f, 0.f);
    #pragma unroll
    for (int j = 0; j < 4; ++j) {
      int cc = 4 * pl + 1 + j;
      if (cc < NPG) {
        int e = g * EPG + cc - 1;
        int child = src[e];
        float lv = lw[e], rv = rw[e];
        float4 hv = *(const float4*)(hp + child * 128 + c4 * 4);
        al.x = fmaf(lv, hv.x, al.x); al.y = fmaf(lv, hv.y, al.y);
        al.z = fmaf(lv, hv.z, al.z); al.w = fmaf(lv, hv.w, al.w);
        ar.x = fmaf(rv, hv.x, ar.x); ar.y = fmaf(rv, hv.y, ar.y);
        ar.z = fmaf(rv, hv.z, ar.z); ar.w = fmaf(rv, hv.w, ar.w);
      }
    }
    *(float4*)&hlS[pw][c4 * 4] = al;
    *(float4*)&hrS[pw][c4 * 4] = ar;
  }
  __syncthreads();

  float acc[2][4] = {};
  int sr = tid >> 3, sc4 = (tid & 7) * 4;

  {
    float4 av = make_float4(0.f, 0.f, 0.f, 0.f);
    if (tid < 128) av = *(const float4*)&hlS[sr][sc4];
    const float* wsrc = Wl;
    int f0 = tid, f1 = tid + 256, f2 = tid + 512, f3 = tid + 768;
    float4 wv0 = *(const float4*)(wsrc + (f0 >> 5) * 128 + (f0 & 31) * 4);
    float4 wv1 = *(const float4*)(wsrc + (f1 >> 5) * 128 + (f1 & 31) * 4);
    float4 wv2 = *(const float4*)(wsrc + (f2 >> 5) * 128 + (f2 & 31) * 4);
    float4 wv3 = *(const float4*)(wsrc + (f3 >> 5) * 128 + (f3 & 31) * 4);
    if (tid < 128) {
      AsT[0][sc4 + 0][sr] = av.x; AsT[0][sc4 + 1][sr] = av.y;
      AsT[0][sc4 + 2][sr] = av.z; AsT[0][sc4 + 3][sr] = av.w;
    }
    *(float4*)&Ws[0][f0 >> 5][(f0 & 31) * 4] = wv0;
    *(float4*)&Ws[0][f1 >> 5][(f1 & 31) * 4] = wv1;
    *(float4*)&Ws[0][f2 >> 5][(f2 & 31) * 4] = wv2;
    *(float4*)&Ws[0][f3 >> 5][(f3 & 31) * 4] = wv3;
  }
  __syncthreads();

  for (int kc = 0; kc < 12; ++kc) {
    int cur = kc & 1, nxt = cur ^ 1;
    if (kc < 11) {
      int kc1 = kc + 1;
      int ssel = kc1 >> 2, kcol = (kc1 & 3) * 32;
      float4 av = make_float4(0.f, 0.f, 0.f, 0.f);
      if (tid < 128) {
        if (ssel == 0)      av = *(const float4*)&hlS[sr][kcol + sc4];
        else if (ssel == 1) av = *(const float4*)&hrS[sr][kcol + sc4];
        else                av = *(const float4*)(hp + (nodeBase + sr) * 128 + kcol + sc4);
      }
      const float* wsrc = ((ssel == 0) ? Wl : (ssel == 1) ? Wr : Wt) + kcol * 128;
      int f0 = tid, f1 = tid + 256, f2 = tid + 512, f3 = tid + 768;
      float4 wv0 = *(const float4*)(wsrc + (f0 >> 5) * 128 + (f0 & 31) * 4);
      float4 wv1 = *(const float4*)(wsrc + (f1 >> 5) * 128 + (f1 & 31) * 4);
      float4 wv2 = *(const float4*)(wsrc + (f2 >> 5) * 128 + (f2 & 31) * 4);
      float4 wv3 = *(const float4*)(wsrc + (f3 >> 5) * 128 + (f3 & 31) * 4);
      if (tid < 128) {
        AsT[nxt][sc4 + 0][sr] = av.x; AsT[nxt][sc4 + 1][sr] = av.y;
        AsT[nxt][sc4 + 2][sr] = av.z; AsT[nxt][sc4 + 3][sr] = av.w;
      }
      *(float4*)&Ws[nxt][f0 >> 5][(f0 & 31) * 4] = wv0;
      *(float4*)&Ws[nxt][f1 >> 5][(f1 & 31) * 4] = wv1;
      *(float4*)&Ws[nxt][f2 >> 5][(f2 & 31) * 4] = wv2;
      *(float4*)&Ws[nxt][f3 >> 5][(f3 & 31) * 4] = wv3;
    }
    #pragma unroll
    for (int kk = 0; kk < 32; ++kk) {
      float4 wv = *(float4*)&Ws[cur][kk][tx * 4];
      float2 av2 = *(float2*)&AsT[cur][kk][ty * 2];
      float aa[2] = {av2.x, av2.y};
      float ww[4] = {wv.x, wv.y, wv.z, wv.w};
      #pragma unroll
      for (int i = 0; i < 2; ++i)
        #pragma unroll
        for (int j = 0; j < 4; ++j)
          acc[i][j] = fmaf(aa[i], ww[j], acc[i][j]);
    }
    if (kc != 11) __syncthreads();
  }
  float4 bv = *(const float4*)(bias + tx * 4);
  float bb[4] = {bv.x, bv.y, bv.z, bv.w};
  #pragma unroll
  for (int i = 0; i < 2; ++i) {
    int r = ty * 2 + i;
    float4 o = make_float4(fmaxf(acc[i][0] + bb[0], 0.f),
                           fmaxf(acc[i][1] + bb[1], 0.f),
                           fmaxf(acc[i][2] + bb[2], 0.f),
                           fmaxf(acc[i][3] + bb[3], 0.f));
    *(float4*)(feat + (rowBase + r) * 128 + tx * 4) = o;
    *(float4*)(hn + (nodeBase + r) * 128 + tx * 4) = o;
  }
}

// ---------------- l2 norms over [H, L] per node ----------------------------
__global__ void k_l2(const float* __restrict__ h, const float* __restrict__ feat,
                     float* __restrict__ l2) {
  int wid = (blockIdx.x * 256 + threadIdx.x) >> 6;   // node id
  int lane = threadIdx.x & 63;
  int g = wid >> 10, local = wid & 1023;
  float s = 0.f;
  if (local >= INT_PG) {                              // leaf: 4*||h0||^2
    const float* p = h + wid * 128;
    float a = p[lane], b = p[lane + 64];
    s = (a * a + b * b) * 4.f;
  } else {
    int row = (g * INT_PG + local) * 128;
    #pragma unroll
    for (int l = 0; l < 4; ++l) {
      const float* p = feat + l * (M_INT * 128) + row;
      float a = p[lane], b = p[lane + 64];
      s += a * a + b * b;
    }
  }
  #pragma unroll
  for (int off = 32; off; off >>= 1) s += __shfl_down(s, off);
  if (lane == 0) l2[wid] = s;
}

// ------ fused top-8 + buildU: one block per graph --------------------------
__global__ __launch_bounds__(256) void k_topsel(const float* __restrict__ l2,
                                                const float* __restrict__ h,
                                                const float* __restrict__ feat,
                                                float* __restrict__ U,
                                                float* __restrict__ Vsum) {
  __shared__ int ssel[8];
  int g = blockIdx.x, tid = threadIdx.x;
  int lane = tid & 63;
  if (tid < 64) {
    unsigned long long kk[16];
    #pragma unroll
    for (int k = 0; k < 16; ++k) {
      int i = k * 64 + lane;
      unsigned vb = __float_as_uint(l2[g * 1024 + i]);  // l2 >= 0: uint order ok
      kk[k] = ((unsigned long long)vb << 32) | (unsigned)(~i);
    }
    for (int r = 0; r < 8; ++r) {
      unsigned long long best = 0ULL;
      #pragma unroll
      for (int k = 0; k < 16; ++k) best = (kk[k] > best) ? kk[k] : best;
      #pragma unroll
      for (int off = 32; off; off >>= 1) {
        unsigned long long o = __shfl_down(best, off);
        best = (o > best) ? o : best;
      }
      best = __shfl(best, 0);
      if (lane == 0) ssel[r] = (int)(~(unsigned)(best & 0xffffffffu));
      #pragma unroll
      for (int k = 0; k < 16; ++k) if (kk[k] == best) kk[k] = 0ULL;
    }
  }
  __syncthreads();
  for (int t = 0; t < 4; ++t) {
    int idx = t * 256 + tid;                  // 0..1023
    int rank = idx >> 7, hh = idx & 127;
    int local = ssel[rank];
    float4 v;
    if (local >= INT_PG) {
      float x = h[(g * NPG + local) * 128 + hh];
      v = make_float4(x, x, x, x);
    } else {
      int row = (g * INT_PG + local) * 128 + hh;
      v.x = feat[row];
      v.y = feat[M_INT * 128 + row];
      v.z = feat[2 * M_INT * 128 + row];
      v.w = feat[3 * M_INT * 128 + row];
    }
    int o = g * 1024 + rank * 128 + hh;
    ((float4*)U)[o] = v;
    ((float4*)Vsum)[o] = v;
  }
}

// ------------------ fused back half: VTS x3 + routing x3 -------------------
// Decentralized barriers: per-block flags (64B stride) + aggregated go word.
// No shared-line RMWs anywhere.
#define GBAR_GLOBAL() do {                                                    \
    __threadfence();                                                          \
    __syncthreads();                                                          \
    ++bkG;                                                                    \
    if (blockIdx.x == 0) {                                                    \
      if (tid >= 1 && tid < NBK)                                              \
        while (__hip_atomic_load(&barm[tid * 16], __ATOMIC_ACQUIRE,           \
                                 __HIP_MEMORY_SCOPE_AGENT) < (unsigned)bkG)   \
          __builtin_amdgcn_s_sleep(1);                                        \
      __syncthreads();                                                        \
      if (tid == 0)                                                           \
        __hip_atomic_store(&barm[GO_OFF], (unsigned)bkG, __ATOMIC_RELEASE,    \
                           __HIP_MEMORY_SCOPE_AGENT);                         \
    } else {                                                                  \
      if (tid == 0) {                                                         \
        __hip_atomic_store(&barm[blockIdx.x * 16], (unsigned)bkG,             \
                           __ATOMIC_RELEASE, __HIP_MEMORY_SCOPE_AGENT);       \
        while (__hip_atomic_load(&barm[GO_OFF], __ATOMIC_ACQUIRE,             \
                                 __HIP_MEMORY_SCOPE_AGENT) < (unsigned)bkG)   \
          __builtin_amdgcn_s_sleep(1);                                        \
      }                                                                       \
      __syncthreads();                                                        \
    }                                                                         \
    __threadfence();                                                          \
  } while (0)

#define GBAR_GROUP() do {                                                     \
    __threadfence();                                                          \
    __syncthreads();                                                          \
    ++bkV;                                                                    \
    int gg_ = blockIdx.x >> 3, mm_ = blockIdx.x & 7;                          \
    if (mm_ == 0) {                                                           \
      if (tid >= 1 && tid < 8)                                                \
        while (__hip_atomic_load(&barm[VFLAG_OFF + (gg_ * 8 + tid) * 16],     \
                                 __ATOMIC_ACQUIRE, __HIP_MEMORY_SCOPE_AGENT)  \
               < (unsigned)bkV)                                               \
          __builtin_amdgcn_s_sleep(1);                                        \
      __syncthreads();                                                        \
      if (tid == 0)                                                           \
        __hip_atomic_store(&barm[VGO_OFF + gg_ * 16], (unsigned)bkV,          \
                           __ATOMIC_RELEASE, __HIP_MEMORY_SCOPE_AGENT);       \
    } else {                                                                  \
      if (tid == 0) {                                                         \
        __hip_atomic_store(&barm[VFLAG_OFF + (gg_ * 8 + mm_) * 16],           \
                           (unsigned)bkV, __ATOMIC_RELEASE,                   \
                           __HIP_MEMORY_SCOPE_AGENT);                         \
        while (__hip_atomic_load(&barm[VGO_OFF + gg_ * 16],                   \
                                 __ATOMIC_ACQUIRE, __HIP_MEMORY_SCOPE_AGENT)  \
               < (unsigned)bkV)                                               \
          __builtin_amdgcn_s_sleep(1);                                        \
      }                                                                       \
      __syncthreads();                                                        \
    }                                                                         \
    __threadfence();                                                          \
  } while (0)

__global__ __launch_bounds__(1024, 4) void k_back(
    const float* __restrict__ U, float* __restrict__ Vsum,
    float* __restrict__ mw, float* __restrict__ sw,
    float* __restrict__ SCT, const float* __restrict__ WT,
    float* __restrict__ gT, float* __restrict__ zpart,
    float* __restrict__ z, float* __restrict__ delta,
    float* __restrict__ out, unsigned* __restrict__ barm) {
  __shared__ __align__(16) char smem[40960];
  int tid = threadIdx.x;
  int bkG = 0, bkV = 0;

  // ===================== VTS: 3 x (A, B) =====================
  for (int it = 0; it < 3; ++it) {
    { // --- phase A: 32 graphs x 8 tiles of 128 rows; 2 rows/thread ---
      float4* Vs2 = (float4*)smem;                       // 64*17 float4
      int g = blockIdx.x >> 3, rb = (blockIdx.x & 7) * 128;
      int p = tid & 15, rp = tid >> 4;
      Vs2[(tid & 63) * 17 + (tid >> 6)] = ((const float4*)Vsum)[g * 1024 + tid];
      __syncthreads();
      int r0 = rb + rp, r1 = rb + 64 + rp;
      float4 u0 = ((const float4*)U)[g * 1024 + r0];
      float4 u1 = ((const float4*)U)[g * 1024 + r1];
      float m0 = -3.4e38f, m1 = -3.4e38f;
      for (int i = 0; i < 64; ++i) {
        float4 v = Vs2[i * 17 + p];
        float a0 = u0.x * v.x + u0.y * v.y + u0.z * v.z + u0.w * v.w;
        float a1 = u1.x * v.x + u1.y * v.y + u1.z * v.z + u1.w * v.w;
        m0 = fmaxf(m0, a0); m1 = fmaxf(m1, a1);
      }
      #pragma unroll
      for (int mk = 8; mk; mk >>= 1) {
        m0 = fmaxf(m0, __shfl_xor(m0, mk));
        m1 = fmaxf(m1, __shfl_xor(m1, mk));
      }
      float s0 = 0.f, s1 = 0.f;
      for (int i = 0; i < 64; ++i) {
        float4 v = Vs2[i * 17 + p];
        float a0 = u0.x * v.x + u0.y * v.y + u0.z * v.z + u0.w * v.w;
        float a1 = u1.x * v.x + u1.y * v.y + u1.z * v.z + u1.w * v.w;
        s0 += __expf(a0 - m0);
        s1 += __expf(a1 - m1);
      }
      #pragma unroll
      for (int mk = 8; mk; mk >>= 1) {
        s0 += __shfl_xor(s0, mk);
        s1 += __shfl_xor(s1, mk);
      }
      if (p == 0) {
        mw[g * 1024 + r0] = m0; sw[g * 1024 + r0] = s0;
        mw[g * 1024 + r1] = m1; sw[g * 1024 + r1] = s1;
      }
    }
    GBAR_GROUP();
    { // --- phase B: 8 tiles of 128 cols; 2 cols/thread ---
      float4* Us2 = (float4*)smem;                       // 17408 B
      float2* Ms2 = (float2*)(smem + 17408);             // 8704 B
      int g = blockIdx.x >> 3, cb = (blockIdx.x & 7) * 128;
      int p = tid & 15, qp = tid >> 4;
      Us2[(tid & 63) * 17 + (tid >> 6)] = ((const float4*)U)[g * 1024 + tid];
      Ms2[(tid & 63) * 17 + (tid >> 6)] =
          make_float2(mw[g * 1024 + tid], 1.0f / sw[g * 1024 + tid]);
      __syncthreads();
      int c0 = cb + qp, c1 = cb + 64 + qp;
      float4 v0 = ((const float4*)Vsum)[g * 1024 + c0];
      float4 v1 = ((const float4*)Vsum)[g * 1024 + c1];
      float4 acc0 = make_float4(0.f, 0.f, 0.f, 0.f);
      float4 acc1 = make_float4(0.f, 0.f, 0.f, 0.f);
      for (int i = 0; i < 64; ++i) {
        float4 uu = Us2[i * 17 + p];
        float2 st = Ms2[i * 17 + p];
        float a0 = uu.x * v0.x + uu.y * v0.y + uu.z * v0.z + uu.w * v0.w;
        float a1 = uu.x * v1.x + uu.y * v1.y + uu.z * v1.z + uu.w * v1.w;
        float w0 = __expf(a0 - st.x) * st.y;
        float w1 = __expf(a1 - st.x) * st.y;
        acc0.x = fmaf(w0, uu.x, acc0.x); acc0.y = fmaf(w0, uu.y, acc0.y);
        acc0.z = fmaf(w0, uu.z, acc0.z); acc0.w = fmaf(w0, uu.w, acc0.w);
        acc1.x = fmaf(w1, uu.x, acc1.x); acc1.y = fmaf(w1, uu.y, acc1.y);
        acc1.z = fmaf(w1, uu.z, acc1.z); acc1.w = fmaf(w1, uu.w, acc1.w);
      }
      #pragma unroll
      for (int mk = 8; mk; mk >>= 1) {
        acc0.x += __shfl_xor(acc0.x, mk); acc0.y += __shfl_xor(acc0.y, mk);
        acc0.z += __shfl_xor(acc0.z, mk); acc0.w += __shfl_xor(acc0.w, mk);
        acc1.x += __shfl_xor(acc1.x, mk); acc1.y += __shfl_xor(acc1.y, mk);
        acc1.z += __shfl_xor(acc1.z, mk); acc1.w += __shfl_xor(acc1.w, mk);
      }
      if (p == 0) {
        if (it == 2) {
          float sq0 = acc0.x * acc0.x + acc0.y * acc0.y + acc0.z * acc0.z + acc0.w * acc0.w;
          float f0 = (sq0 / (1.f + sq0)) / (sqrtf(sq0 + 1e-10f) + 1e-8f);
          ((float4*)SCT)[c0 * 32 + g] =
              make_float4(acc0.x * f0, acc0.y * f0, acc0.z * f0, acc0.w * f0);
          float sq1 = acc1.x * acc1.x + acc1.y * acc1.y + acc1.z * acc1.z + acc1.w * acc1.w;
          float f1 = (sq1 / (1.f + sq1)) / (sqrtf(sq1 + 1e-10f) + 1e-8f);
          ((float4*)SCT)[c1 * 32 + g] =
              make_float4(acc1.x * f1, acc1.y * f1, acc1.z * f1, acc1.w * f1);
        } else {
          float4 w0 = ((const float4*)Vsum)[g * 1024 + c0];
          ((float4*)Vsum)[g * 1024 + c0] = make_float4(w0.x + acc0.x, w0.y + acc0.y,
                                                       w0.z + acc0.z, w0.w + acc0.w);
          float4 w1 = ((const float4*)Vsum)[g * 1024 + c1];
          ((float4*)Vsum)[g * 1024 + c1] = make_float4(w1.x + acc1.x, w1.y + acc1.y,
                                                       w1.z + acc1.z, w1.w + acc1.w);
        }
      }
    }
    if (it == 2) GBAR_GLOBAL(); else GBAR_GROUP();
  }

  // ===================== routing: 3 iterations =====================
  for (int it = 0; it < 3; ++it) {
    { // --- zsweep: 800 virtual 256-thr groups ---
      int vid = blockIdx.x * 4 + (tid >> 8);
      if (vid < 800) {
        int t = tid & 255;
        int sb = vid >> 4, nb = vid & 15;
        int b = t & 31, ch = t >> 5;
        int n0 = nb * 64;
        const float4* wt = (const float4*)WT + (sb * 1024 + n0) * 16;
        const float4* sct = (const float4*)SCT + n0 * 32 + b;
        const float* gp = gT + (sb * 1024 + n0) * 32 + b;
        float a0 = 0.f, a1 = 0.f;
        #pragma unroll 8
        for (int nn = 0; nn < 64; ++nn) {
          float4 w0 = wt[nn * 16 + ch];
          float4 w1 = wt[nn * 16 + ch + 8];
          float4 s4 = sct[nn * 32];
          float gm = (it == 0) ? (1.0f / 50.0f) : gp[nn * 32];
          float t0 = w0.x * s4.x + w0.y * s4.y + w0.z * s4.z + w0.w * s4.w;
          float t1 = w1.x * s4.x + w1.y * s4.y + w1.z * s4.z + w1.w * s4.w;
          a0 = fmaf(gm, t0, a0);
          a1 = fmaf(gm, t1, a1);
        }
        zpart[vid * 512 + t] = a0;
        zpart[vid * 512 + 256 + t] = a1;
      }
    }
    GBAR_GLOBAL();
    { // --- zred: 25 active blocks; squash once per (b,s); last -> logits ---
      if (blockIdx.x < 25) {
        float* sb_ = (float*)smem;             // 4096 B
        float* fb  = (float*)(smem + 4096);    // 256 B
        float* sqb = (float*)(smem + 4352);    // 256 B
        int idx = blockIdx.x * 1024 + tid;     // 25600 = (b*NS+sb)*16+c
        int c = idx & 15;
        int sbk = (idx >> 4) % NS;
        int b = idx / (16 * NS);
        int lofs = (c < 8) ? (c * 32 + b) : (256 + (c - 8) * 32 + b);
        const float* zp = zpart + sbk * 16 * 512 + lofs;
        float s = 0.f;
        #pragma unroll
        for (int nb = 0; nb < 16; ++nb) s += zp[nb * 512];
        sb_[tid] = s;
        __syncthreads();
        if ((tid & 15) == 0) {                 // one lane per (b,s) pair
          float sq = 0.f;
          #pragma unroll
          for (int cc = 0; cc < 16; ++cc) sq += sb_[tid + cc] * sb_[tid + cc];
          float f = (sq / (1.f + sq)) / (sqrtf(sq + 1e-10f) + 1e-8f);
          fb[tid >> 4] = f;
          sqb[tid >> 4] = sq;
        }
        __syncthreads();
        z[idx] = s * fb[tid >> 4];
        if (it == 2 && (tid & 15) == 0) {
          float sq = sqb[tid >> 4], f = fb[tid >> 4];
          float lg = sqrtf(sq * f * f + 1e-10f);
          int pr = idx >> 4;                   // b*NS + s
          out[pr] = lg;
          out[pr + 1600] = lg;
        }
      }
    }
    if (it == 2) break;
    GBAR_GLOBAL();
    { // --- dsweep + gamma: 2 groups x 512 thr, 2 nodes each ---
      int grp = tid >> 9, t = tid & 511;
      char* base = smem + grp * 20480;
      float*  wl   = (float*)base;             // 12800 B  [s][c][m]
      float4* scl  = (float4*)(base + 12800);  //   512 B
      float*  dtot = (float*)(base + 13312);   //  6400 B  [s][b]
      float*  mb   = (float*)(base + 19712);   //   128 B
      float*  ibv  = (float*)(base + 19840);   //   128 B
      for (int k = 0; k < 2; ++k) {
        int n = blockIdx.x * 4 + grp * 2 + k;
        __syncthreads();                       // prev readers done
        for (int i = t; i < 3200; i += 512)
          wl[i] = WT[((i >> 6) * 1024 + n) * 64 + (i & 63)];
        if (t < 32) scl[t] = ((const float4*)SCT)[n * 32 + t];
        __syncthreads();
        for (int idx = t; idx < 1600; idx += 512) {
          int s = idx >> 5, b = idx & 31;
          const float4* wp = (const float4*)(wl + s * 64);
          const float4* zp = (const float4*)(z + (b * 50 + s) * 16);
          float4 z0 = zp[0], z1 = zp[1], z2 = zp[2], z3 = zp[3];
          float zs[16] = {z0.x, z0.y, z0.z, z0.w, z1.x, z1.y, z1.z, z1.w,
                          z2.x, z2.y, z2.z, z2.w, z3.x, z3.y, z3.z, z3.w};
          float4 y = make_float4(0.f, 0.f, 0.f, 0.f);
          #pragma unroll
          for (int c = 0; c < 16; ++c) {
            float4 w = wp[c];
            float zc = zs[c];
            y.x = fmaf(zc, w.x, y.x); y.y = fmaf(zc, w.y, y.y);
            y.z = fmaf(zc, w.z, y.z); y.w = fmaf(zc, w.w, y.w);
          }
          float4 sc = scl[b];
          float dd = sc.x * y.x + sc.y * y.y + sc.z * y.z + sc.w * y.w;
          float dt = (it == 0) ? dd : (delta[(s * 1024 + n) * 32 + b] + dd);
          dtot[s * 32 + b] = dt;
          if (it == 0) delta[(s * 1024 + n) * 32 + b] = dt;
        }
        __syncthreads();
        if (t < 32) {                          // softmax stats over s
          float m = -3.4e38f;
          for (int s = 0; s < NS; ++s) m = fmaxf(m, dtot[s * 32 + t]);
          float sum = 0.f;
          for (int s = 0; s < NS; ++s) sum += __expf(dtot[s * 32 + t] - m);
          mb[t] = m; ibv[t] = 1.0f / sum;
        }
        __syncthreads();
        for (int idx = t; idx < 1600; idx += 512) {
          int s = idx >> 5, b = idx & 31;
          gT[(s * 1024 + n) * 32 + b] = __expf(dtot[s * 32 + b] - mb[b]) * ibv[b];
        }
      }
    }
    GBAR_GLOBAL();
  }
}

// ---------------------------------------------------------------------------
extern "C" void kernel_launch(void* const* d_in, const int* in_sizes, int n_in,
                              void* d_out, int out_size, void* d_ws, size_t ws_size,
                              hipStream_t stream) {
  const int*   type_ids  = (const int*)d_in[0];
  const int*   token_ids = (const int*)d_in[1];
  const int*   src       = (const int*)d_in[2];
  const float* lw        = (const float*)d_in[4];
  const float* rw        = (const float*)d_in[5];
  const float* temb      = (const float*)d_in[7];
  const float* kemb      = (const float*)d_in[8];
  const float* Wl        = (const float*)d_in[9];
  const float* Wr        = (const float*)d_in[10];
  const float* Wt        = (const float*)d_in[11];
  const float* bconv     = (const float*)d_in[12];
  const float* Wjm       = (const float*)d_in[13];
  float* out = (float*)d_out;
  char* wsb = (char*)d_ws;

  // workspace layout (~81 MB used; ws is 256 MiB; no overlays)
  float* hA    = (float*)(wsb + 0);          // 16.78 MB (ping)
  float* hB    = (float*)(wsb + 16777216);   // 16.78 MB (pong)
  float* feat  = (float*)(wsb + 33554432);   // 16.78 MB
  float* WT    = (float*)(wsb + 50331648);   // 13.11 MB
  float* delta = (float*)(wsb + 63438848);   // 6.55  MB
  float* gT    = (float*)(wsb + 69992448);   // 6.55  MB
  float* z     = (float*)(wsb + 76546048);   // 100 KB (squashed z)
  float* l2b   = (float*)(wsb + 76853248);   // 128 KB
  float* U     = (float*)(wsb + 76984320);   // 512 KB
  float* Vsum  = (float*)(wsb + 77508608);   // 512 KB
  float* mw    = (float*)(wsb + 78032896);   // 128 KB
  float* sw    = (float*)(wsb + 78163968);   // 128 KB
  float* SCT   = (float*)(wsb + 78295040);   // 512 KB
  float* zpart = (float*)(wsb + 78819328);   // 1.64 MB (800 x 512)
  unsigned* barm = (unsigned*)(wsb + 80478208);  // 8720 u32 (zeroed in k_init)

  k_init<<<5120, 256, 0, stream>>>(type_ids, token_ids, temb, kemb, hA, hB,
                                   Wjm, WT, barm);

  for (int l = 0; l < NLAY; ++l) {
    const float* hp = (l & 1) ? hB : hA;
    float*       hn = (l & 1) ? hA : hB;
    k_conv<<<512, 256, 0, stream>>>(hp, hn, src, lw, rw,
                                    Wl + l * 16384, Wr + l * 16384, Wt + l * 16384,
                                    bconv + l * 128, feat + l * (M_INT * 128));
  }

  // after 4 layers: internal nodes live in hA; leaves in hA since embed
  k_l2<<<8192, 256, 0, stream>>>(hA, feat, l2b);
  k_topsel<<<32, 256, 0, stream>>>(l2b, hA, feat, U, Vsum);

  k_back<<<NBK, 1024, 0, stream>>>(U, Vsum, mw, sw, SCT, WT, gT, zpart, z,
                                   delta, out, barm);
}

// Round 11
// 432.221 us; speedup vs baseline: 6.6065x; 6.6065x over previous
//
#include <hip/hip_runtime.h>

// ---------------------------------------------------------------------------
// TreeCaps forward, MI355X fp32 implementation.
// Fixed forest: per graph of 1024 nodes, node p's children are 4p+1..4p+4;
// nodes 0..255 are internal (updated each layer), 256..1023 are leaves.
// R2: k_dsweep 1 block per node -> WT read exactly once.
// R3: conv fusion at 1 block/CU -> regression (staging serialized).
// R4: occupancy attack -> WIN (523->476).
// R5: conv gather-fusion retry + K-loop dbuf -> NEUTRAL (477); kept.
// R6: VTS shfl_xor rewrite; zsweep grid 1600 -> atomics regression (518).
// R7: zsweep atomics eliminated (2-stage partial-sum) -> WIN (518->432).
// R8: VTS 256-thr reg-blocking -> REGRESSION (468): 2 waves/SIMD cliff.
// R9: revert VTS to 1024-thr; keep zred-squash/logits fusion + k_init -> 434.
// R10-R12: fused back half with software grid barriers (counter-RMW, load-
//     poll, decentralized flags) -> all CORRECT, all ~2400-2800us. Root
//     cause: agent-scope __threadfence = cross-XCD L2 writeback/invalidate
//     per barrier -> every phase re-reads its working set from cold HBM
//     (FETCH_SIZE 93-170 MB vs ~30 MB multi-kernel). Software grid barriers
//     on this chip cost ~200us each regardless of arrival scheme; the
//     hardware dispatch boundary does the same flush in ~5-10us. Fused
//     path abandoned.
// R13: revert to R9 verbatim (best verified: 434.2us).
// ---------------------------------------------------------------------------

#define BG      32
#define NPG     1024
#define HH      128
#define NLAY    4
#define INT_PG  256
#define M_INT   8192      // BG*INT_PG
#define NN      32768     // BG*NPG
#define EPG     1023
#define DCC     16
#define NS      50

// ---- init: embed h0 (leaves to both bufs) + transpose Wjm -> WT -----------
__global__ void k_init(const int* __restrict__ tids, const int* __restrict__ kids,
                       const float* __restrict__ temb, const float* __restrict__ kemb,
                       float* __restrict__ hA, float* __restrict__ hB,
                       const float* __restrict__ Wjm, float* __restrict__ WT) {
  __shared__ float w[3200];
  int tid = threadIdx.x;
  if (blockIdx.x < 4096) {                         // ---- embed part
    int idx = blockIdx.x * 256 + tid;              // NN*32
    int n = idx >> 5, c4 = idx & 31;
    float4 v;
    if (c4 < 16) v = *(const float4*)(temb + tids[n] * 64 + c4 * 4);
    else         v = *(const float4*)(kemb + kids[n] * 64 + (c4 - 16) * 4);
    *(float4*)(hA + n * 128 + c4 * 4) = v;
    if ((n & 1023) >= INT_PG)                      // leaves constant in both bufs
      *(float4*)(hB + n * 128 + c4 * 4) = v;
  } else {                                         // ---- transW part
    int n = blockIdx.x - 4096;
    for (int i = tid; i < 3200; i += 256) w[i] = Wjm[n * 3200 + i];
    __syncthreads();
    for (int i = tid; i < 3200; i += 256) {
      int s = i >> 6, cm = i & 63;
      int cc = cm >> 2, m = cm & 3;
      WT[(s * 1024 + n) * 64 + cm] = w[(cc * NS + s) * 4 + m];
    }
  }
}

// --- fused gather+conv: new_h = relu(hl@Wl + hr@Wr + h@Wt + b) -------------
// [8192 rows, K=384, N=128]; block = 256 thr, 16 rows x 128 cols, 2x4/thread.
// 512 blocks (2/CU). Children of the block's 16 parents = contiguous local
// slice staged to LDS with k_gather's exact fma order. K-loop double-buffered.
__global__ __launch_bounds__(256) void k_conv(
    const float* __restrict__ hp, float* __restrict__ hn,
    const int* __restrict__ src, const float* __restrict__ lw,
    const float* __restrict__ rw,
    const float* __restrict__ Wl, const float* __restrict__ Wr,
    const float* __restrict__ Wt, const float* __restrict__ bias,
    float* __restrict__ feat) {
  __shared__ float Ws[2][32][128];   // 32 KB
  __shared__ float AsT[2][32][20];   // 5 KB, padded
  __shared__ float hlS[16][128];     // 8 KB
  __shared__ float hrS[16][128];     // 8 KB
  int tid = threadIdx.x;
  int tx = tid & 31, ty = tid >> 5;          // ty 0..7 -> rows 2*ty, 2*ty+1
  int rowBase = blockIdx.x * 16;
  int g = rowBase >> 8, plBase = rowBase & 255;
  int nodeBase = g * NPG + plBase;

  // ---- stage weighted child sums for 16 parents (k_gather fma order) ----
  #pragma unroll
  for (int t = 0; t < 2; ++t) {
    int it = t * 256 + tid;                  // 0..511
    int pw = it >> 5, c4 = it & 31;
    int pl = plBase + pw;
    float4 al = make_float4(0.f, 0.f, 0.f, 0.f);
    float4 ar = make_float4(0.f, 0.f, 0.f, 0.f);
    #pragma unroll
    for (int j = 0; j < 4; ++j) {
      int cc = 4 * pl + 1 + j;
      if (cc < NPG) {
        int e = g * EPG + cc - 1;
        int child = src[e];
        float lv = lw[e], rv = rw[e];
        float4 hv = *(const float4*)(hp + child * 128 + c4 * 4);
        al.x = fmaf(lv, hv.x, al.x); al.y = fmaf(lv, hv.y, al.y);
        al.z = fmaf(lv, hv.z, al.z); al.w = fmaf(lv, hv.w, al.w);
        ar.x = fmaf(rv, hv.x, ar.x); ar.y = fmaf(rv, hv.y, ar.y);
        ar.z = fmaf(rv, hv.z, ar.z); ar.w = fmaf(rv, hv.w, ar.w);
      }
    }
    *(float4*)&hlS[pw][c4 * 4] = al;
    *(float4*)&hrS[pw][c4 * 4] = ar;
  }
  __syncthreads();

  float acc[2][4] = {};
  int sr = tid >> 3, sc4 = (tid & 7) * 4;    // valid for tid<128: sr 0..15

  // prologue: load kc=0 into buffer 0 (ssel=0 -> hlS)
  {
    float4 av = make_float4(0.f, 0.f, 0.f, 0.f);
    if (tid < 128) av = *(const float4*)&hlS[sr][sc4];
    const float* wsrc = Wl;                  // kcol = 0
    int f0 = tid, f1 = tid + 256, f2 = tid + 512, f3 = tid + 768;
    float4 wv0 = *(const float4*)(wsrc + (f0 >> 5) * 128 + (f0 & 31) * 4);
    float4 wv1 = *(const float4*)(wsrc + (f1 >> 5) * 128 + (f1 & 31) * 4);
    float4 wv2 = *(const float4*)(wsrc + (f2 >> 5) * 128 + (f2 & 31) * 4);
    float4 wv3 = *(const float4*)(wsrc + (f3 >> 5) * 128 + (f3 & 31) * 4);
    if (tid < 128) {
      AsT[0][sc4 + 0][sr] = av.x; AsT[0][sc4 + 1][sr] = av.y;
      AsT[0][sc4 + 2][sr] = av.z; AsT[0][sc4 + 3][sr] = av.w;
    }
    *(float4*)&Ws[0][f0 >> 5][(f0 & 31) * 4] = wv0;
    *(float4*)&Ws[0][f1 >> 5][(f1 & 31) * 4] = wv1;
    *(float4*)&Ws[0][f2 >> 5][(f2 & 31) * 4] = wv2;
    *(float4*)&Ws[0][f3 >> 5][(f3 & 31) * 4] = wv3;
  }
  __syncthreads();

  for (int kc = 0; kc < 12; ++kc) {
    int cur = kc & 1, nxt = cur ^ 1;
    if (kc < 11) {                           // prefetch kc+1 into nxt
      int kc1 = kc + 1;
      int ssel = kc1 >> 2, kcol = (kc1 & 3) * 32;
      float4 av = make_float4(0.f, 0.f, 0.f, 0.f);
      if (tid < 128) {
        if (ssel == 0)      av = *(const float4*)&hlS[sr][kcol + sc4];
        else if (ssel == 1) av = *(const float4*)&hrS[sr][kcol + sc4];
        else                av = *(const float4*)(hp + (nodeBase + sr) * 128 + kcol + sc4);
      }
      const float* wsrc = ((ssel == 0) ? Wl : (ssel == 1) ? Wr : Wt) + kcol * 128;
      int f0 = tid, f1 = tid + 256, f2 = tid + 512, f3 = tid + 768;
      float4 wv0 = *(const float4*)(wsrc + (f0 >> 5) * 128 + (f0 & 31) * 4);
      float4 wv1 = *(const float4*)(wsrc + (f1 >> 5) * 128 + (f1 & 31) * 4);
      float4 wv2 = *(const float4*)(wsrc + (f2 >> 5) * 128 + (f2 & 31) * 4);
      float4 wv3 = *(const float4*)(wsrc + (f3 >> 5) * 128 + (f3 & 31) * 4);
      if (tid < 128) {
        AsT[nxt][sc4 + 0][sr] = av.x; AsT[nxt][sc4 + 1][sr] = av.y;
        AsT[nxt][sc4 + 2][sr] = av.z; AsT[nxt][sc4 + 3][sr] = av.w;
      }
      *(float4*)&Ws[nxt][f0 >> 5][(f0 & 31) * 4] = wv0;
      *(float4*)&Ws[nxt][f1 >> 5][(f1 & 31) * 4] = wv1;
      *(float4*)&Ws[nxt][f2 >> 5][(f2 & 31) * 4] = wv2;
      *(float4*)&Ws[nxt][f3 >> 5][(f3 & 31) * 4] = wv3;
    }
    #pragma unroll
    for (int kk = 0; kk < 32; ++kk) {
      float4 wv = *(float4*)&Ws[cur][kk][tx * 4];
      float2 av2 = *(float2*)&AsT[cur][kk][ty * 2];
      float aa[2] = {av2.x, av2.y};
      float ww[4] = {wv.x, wv.y, wv.z, wv.w};
      #pragma unroll
      for (int i = 0; i < 2; ++i)
        #pragma unroll
        for (int j = 0; j < 4; ++j)
          acc[i][j] = fmaf(aa[i], ww[j], acc[i][j]);
    }
    if (kc != 11) __syncthreads();
  }
  float4 bv = *(const float4*)(bias + tx * 4);
  float bb[4] = {bv.x, bv.y, bv.z, bv.w};
  #pragma unroll
  for (int i = 0; i < 2; ++i) {
    int r = ty * 2 + i;
    float4 o = make_float4(fmaxf(acc[i][0] + bb[0], 0.f),
                           fmaxf(acc[i][1] + bb[1], 0.f),
                           fmaxf(acc[i][2] + bb[2], 0.f),
                           fmaxf(acc[i][3] + bb[3], 0.f));
    *(float4*)(feat + (rowBase + r) * 128 + tx * 4) = o;
    *(float4*)(hn + (nodeBase + r) * 128 + tx * 4) = o;
  }
}

// ---------------- l2 norms over [H, L] per node ----------------------------
__global__ void k_l2(const float* __restrict__ h, const float* __restrict__ feat,
                     float* __restrict__ l2) {
  int wid = (blockIdx.x * 256 + threadIdx.x) >> 6;   // node id
  int lane = threadIdx.x & 63;
  int g = wid >> 10, local = wid & 1023;
  float s = 0.f;
  if (local >= INT_PG) {                              // leaf: 4*||h0||^2
    const float* p = h + wid * 128;
    float a = p[lane], b = p[lane + 64];
    s = (a * a + b * b) * 4.f;
  } else {
    int row = (g * INT_PG + local) * 128;
    #pragma unroll
    for (int l = 0; l < 4; ++l) {
      const float* p = feat + l * (M_INT * 128) + row;
      float a = p[lane], b = p[lane + 64];
      s += a * a + b * b;
    }
  }
  #pragma unroll
  for (int off = 32; off; off >>= 1) s += __shfl_down(s, off);
  if (lane == 0) l2[wid] = s;
}

// ------ fused top-8 + buildU: one block per graph --------------------------
__global__ __launch_bounds__(256) void k_topsel(const float* __restrict__ l2,
                                                const float* __restrict__ h,
                                                const float* __restrict__ feat,
                                                float* __restrict__ U,
                                                float* __restrict__ Vsum) {
  __shared__ int ssel[8];
  int g = blockIdx.x, tid = threadIdx.x;
  int lane = tid & 63;
  if (tid < 64) {
    unsigned long long kk[16];
    #pragma unroll
    for (int k = 0; k < 16; ++k) {
      int i = k * 64 + lane;
      unsigned vb = __float_as_uint(l2[g * 1024 + i]);  // l2 >= 0: uint order ok
      kk[k] = ((unsigned long long)vb << 32) | (unsigned)(~i);
    }
    for (int r = 0; r < 8; ++r) {
      unsigned long long best = 0ULL;
      #pragma unroll
      for (int k = 0; k < 16; ++k) best = (kk[k] > best) ? kk[k] : best;
      #pragma unroll
      for (int off = 32; off; off >>= 1) {
        unsigned long long o = __shfl_down(best, off);
        best = (o > best) ? o : best;
      }
      best = __shfl(best, 0);
      if (lane == 0) ssel[r] = (int)(~(unsigned)(best & 0xffffffffu));
      #pragma unroll
      for (int k = 0; k < 16; ++k) if (kk[k] == best) kk[k] = 0ULL;
    }
  }
  __syncthreads();
  for (int t = 0; t < 4; ++t) {
    int idx = t * 256 + tid;                  // 0..1023
    int rank = idx >> 7, hh = idx & 127;
    int local = ssel[rank];
    float4 v;
    if (local >= INT_PG) {
      float x = h[(g * NPG + local) * 128 + hh];
      v = make_float4(x, x, x, x);
    } else {
      int row = (g * INT_PG + local) * 128 + hh;
      v.x = feat[row];
      v.y = feat[M_INT * 128 + row];
      v.z = feat[2 * M_INT * 128 + row];
      v.w = feat[3 * M_INT * 128 + row];
    }
    int o = g * 1024 + rank * 128 + hh;
    ((float4*)U)[o] = v;
    ((float4*)Vsum)[o] = v;
  }
}

// ------------- VTS phase A: per-row softmax stats of alpha = U@Vsum.T ------
// 1024-thr (32 waves/CU). p = tid&15 (j-chunk of 64), r = tid>>4;
// shfl_xor(8,4,2,1) = old LDS-tree pairing, bit-exact.
__global__ __launch_bounds__(1024) void k_vtsA(const float* __restrict__ U,
                                               const float* __restrict__ Vsum,
                                               float* __restrict__ mw, float* __restrict__ sw) {
  __shared__ float4 Vs2[64 * 17];   // 17.4 KB; elem j=p*64+i at [i*17+p]
  int g = blockIdx.x >> 4, rb = (blockIdx.x & 15) * 64;
  int tid = threadIdx.x, p = tid & 15, r = tid >> 4;
  Vs2[(tid & 63) * 17 + (tid >> 6)] = ((const float4*)Vsum)[g * 1024 + tid];
  __syncthreads();
  float4 u = ((const float4*)U)[g * 1024 + rb + r];
  float m = -3.4e38f;
  for (int i = 0; i < 64; ++i) {
    float4 v = Vs2[i * 17 + p];
    float a = u.x * v.x + u.y * v.y + u.z * v.z + u.w * v.w;
    m = fmaxf(m, a);
  }
  #pragma unroll
  for (int mk = 8; mk; mk >>= 1) m = fmaxf(m, __shfl_xor(m, mk));
  float s = 0.f;
  for (int i = 0; i < 64; ++i) {
    float4 v = Vs2[i * 17 + p];
    float a = u.x * v.x + u.y * v.y + u.z * v.z + u.w * v.w;
    s += __expf(a - m);
  }
  #pragma unroll
  for (int mk = 8; mk; mk >>= 1) s += __shfl_xor(s, mk);
  if (p == 0) {
    mw[g * 1024 + rb + r] = m;
    sw[g * 1024 + rb + r] = s;
  }
}

// ------------- VTS phase B: Vnew = beta.T @ U; update Vsum or emit SC ------
__global__ __launch_bounds__(1024) void k_vtsB(const float* __restrict__ U,
                                               float* __restrict__ Vsum,
                                               const float* __restrict__ mw,
                                               const float* __restrict__ sw,
                                               float* __restrict__ SCT, int last) {
  __shared__ float4 Us2[64 * 17];   // 17.4 KB; row i of chunk p at [i*17+p]
  __shared__ float2 Ms2[64 * 17];   // 8.7 KB  (m, 1/s)
  int g = blockIdx.x >> 4, cb = (blockIdx.x & 15) * 64;
  int tid = threadIdx.x, p = tid & 15, q = tid >> 4;
  Us2[(tid & 63) * 17 + (tid >> 6)] = ((const float4*)U)[g * 1024 + tid];
  Ms2[(tid & 63) * 17 + (tid >> 6)] =
      make_float2(mw[g * 1024 + tid], 1.0f / sw[g * 1024 + tid]);
  __syncthreads();
  float4 v = ((const float4*)Vsum)[g * 1024 + cb + q];
  float4 acc = make_float4(0.f, 0.f, 0.f, 0.f);
  for (int i = 0; i < 64; ++i) {
    float4 uu = Us2[i * 17 + p];
    float2 st = Ms2[i * 17 + p];
    float a = uu.x * v.x + uu.y * v.y + uu.z * v.z + uu.w * v.w;
    float w = __expf(a - st.x) * st.y;
    acc.x = fmaf(w, uu.x, acc.x); acc.y = fmaf(w, uu.y, acc.y);
    acc.z = fmaf(w, uu.z, acc.z); acc.w = fmaf(w, uu.w, acc.w);
  }
  #pragma unroll
  for (int mk = 8; mk; mk >>= 1) {
    acc.x += __shfl_xor(acc.x, mk);
    acc.y += __shfl_xor(acc.y, mk);
    acc.z += __shfl_xor(acc.z, mk);
    acc.w += __shfl_xor(acc.w, mk);
  }
  if (p == 0) {
    float4 o = acc;
    int jc = cb + q;
    if (last) {
      float sq = o.x * o.x + o.y * o.y + o.z * o.z + o.w * o.w;
      float f = (sq / (1.f + sq)) / (sqrtf(sq + 1e-10f) + 1e-8f);
      ((float4*)SCT)[jc * 32 + g] = make_float4(o.x * f, o.y * f, o.z * f, o.w * f);
    } else {
      float4 w0 = ((const float4*)Vsum)[g * 1024 + jc];
      ((float4*)Vsum)[g * 1024 + jc] = make_float4(w0.x + o.x, w0.y + o.y,
                                                   w0.z + o.z, w0.w + o.w);
    }
  }
}

// ------------- Z sweep stage 1: partial sums, NO atomics -------------------
// grid 800 = 50 sb x 16 nb, 64 n each; plain coalesced stores (L2-resident).
__global__ __launch_bounds__(256) void k_zsweep(const float* __restrict__ WT,
                                                const float* __restrict__ SCT,
                                                const float* __restrict__ gT,
                                                float* __restrict__ zpart, int it0) {
  int sb = blockIdx.x >> 4, nb = blockIdx.x & 15;
  int tid = threadIdx.x;
  int b = tid & 31, ch = tid >> 5;             // ch in 0..7: c = ch, ch+8
  int n0 = nb * 64;
  const float4* wt = (const float4*)WT + (sb * 1024 + n0) * 16;
  const float4* sct = (const float4*)SCT + n0 * 32 + b;
  const float* gp = gT + (sb * 1024 + n0) * 32 + b;
  float a0 = 0.f, a1 = 0.f;
  #pragma unroll 8
  for (int nn = 0; nn < 64; ++nn) {
    float4 w0 = wt[nn * 16 + ch];
    float4 w1 = wt[nn * 16 + ch + 8];
    float4 s4 = sct[nn * 32];
    float gm = it0 ? (1.0f / 50.0f) : gp[nn * 32];
    float t0 = w0.x * s4.x + w0.y * s4.y + w0.z * s4.z + w0.w * s4.w;
    float t1 = w1.x * s4.x + w1.y * s4.y + w1.z * s4.z + w1.w * s4.w;
    a0 = fmaf(gm, t0, a0);
    a1 = fmaf(gm, t1, a1);
  }
  zpart[blockIdx.x * 512 + tid] = a0;
  zpart[blockIdx.x * 512 + 256 + tid] = a1;
}

// ---- Z sweep stage 2: accZ sum + squash -> z; final iter also logits ------
// Squash computed ONCE per (b,s) (sequential c-order -> bit-exact).
__global__ void k_zred(const float* __restrict__ zpart, float* __restrict__ z,
                       float* __restrict__ out, int last) {
  __shared__ float sb_[256];
  __shared__ float fb[16];
  __shared__ float sqb[16];
  int tid = threadIdx.x;
  int idx = blockIdx.x * 256 + tid;            // 25600 = (b*NS+sb)*16+c
  int c = idx & 15;
  int sbk = (idx >> 4) % NS;
  int b = idx / (16 * NS);
  int lofs = (c < 8) ? (c * 32 + b) : (256 + (c - 8) * 32 + b);
  const float* zp = zpart + sbk * 16 * 512 + lofs;
  float s = 0.f;
  #pragma unroll
  for (int nb = 0; nb < 16; ++nb) s += zp[nb * 512];
  sb_[tid] = s;
  __syncthreads();
  if ((tid & 15) == 0) {                       // one lane per (b,s) pair
    float sq = 0.f;
    #pragma unroll
    for (int cc = 0; cc < 16; ++cc) sq += sb_[tid + cc] * sb_[tid + cc];
    float f = (sq / (1.f + sq)) / (sqrtf(sq + 1e-10f) + 1e-8f);
    fb[tid >> 4] = f;
    sqb[tid >> 4] = sq;
  }
  __syncthreads();
  z[idx] = s * fb[tid >> 4];
  if (last && (tid & 15) == 0) {
    float sq = sqb[tid >> 4], f = fb[tid >> 4];
    float lg = sqrtf(sq * f * f + 1e-10f);
    int pr = idx >> 4;                         // b*NS + s
    out[pr] = lg;
    out[pr + 1600] = lg;
  }
}

// -- D sweep + gamma: dtot = delta_old + <v,z>; gT = softmax_s(dtot) --------
// Reads pre-squashed z (squash moved to k_zred).
__global__ __launch_bounds__(256) void k_dsweep(const float* __restrict__ WT,
                                                const float* __restrict__ SCT,
                                                const float* __restrict__ z,
                                                float* __restrict__ delta,
                                                float* __restrict__ gT, int first) {
  __shared__ float wl[50 * 64];     // [s][c][m]  12.8 KB
  __shared__ float4 scl[32];        // SCT[n][b][:]
  __shared__ float dtot[NS][32];    // 6.4 KB
  __shared__ float mb[32], ib[32];
  int n = blockIdx.x;
  int tid = threadIdx.x;
  for (int i = tid; i < 3200; i += 256)
    wl[i] = WT[((i >> 6) * 1024 + n) * 64 + (i & 63)];
  if (tid < 32) scl[tid] = ((const float4*)SCT)[n * 32 + tid];
  __syncthreads();
  for (int idx = tid; idx < 1600; idx += 256) {
    int s = idx >> 5, b = idx & 31;              // lanes 0-31: same s (LDS bcast)
    const float4* wp = (const float4*)(wl + s * 64);
    const float4* zp = (const float4*)(z + (b * 50 + s) * 16);
    float4 z0 = zp[0], z1 = zp[1], z2 = zp[2], z3 = zp[3];
    float zs[16] = {z0.x, z0.y, z0.z, z0.w, z1.x, z1.y, z1.z, z1.w,
                    z2.x, z2.y, z2.z, z2.w, z3.x, z3.y, z3.z, z3.w};
    float4 y = make_float4(0.f, 0.f, 0.f, 0.f);
    #pragma unroll
    for (int c = 0; c < 16; ++c) {
      float4 w = wp[c];
      float zc = zs[c];
      y.x = fmaf(zc, w.x, y.x); y.y = fmaf(zc, w.y, y.y);
      y.z = fmaf(zc, w.z, y.z); y.w = fmaf(zc, w.w, y.w);
    }
    float4 sc = scl[b];
    float dd = sc.x * y.x + sc.y * y.y + sc.z * y.z + sc.w * y.w;
    float dt = first ? dd : (delta[(s * 1024 + n) * 32 + b] + dd);
    dtot[s][b] = dt;
    if (first) delta[(s * 1024 + n) * 32 + b] = dt;  // needed by next dsweep
  }
  __syncthreads();
  if (tid < 32) {                                    // softmax stats over s
    float m = -3.4e38f;
    for (int s = 0; s < NS; ++s) m = fmaxf(m, dtot[s][tid]);
    float sum = 0.f;
    for (int s = 0; s < NS; ++s) sum += __expf(dtot[s][tid] - m);
    mb[tid] = m; ib[tid] = 1.0f / sum;
  }
  __syncthreads();
  for (int idx = tid; idx < 1600; idx += 256) {
    int s = idx >> 5, b = idx & 31;
    gT[(s * 1024 + n) * 32 + b] = __expf(dtot[s][b] - mb[b]) * ib[b];
  }
}

// ---------------------------------------------------------------------------
extern "C" void kernel_launch(void* const* d_in, const int* in_sizes, int n_in,
                              void* d_out, int out_size, void* d_ws, size_t ws_size,
                              hipStream_t stream) {
  const int*   type_ids  = (const int*)d_in[0];
  const int*   token_ids = (const int*)d_in[1];
  const int*   src       = (const int*)d_in[2];
  const float* lw        = (const float*)d_in[4];
  const float* rw        = (const float*)d_in[5];
  const float* temb      = (const float*)d_in[7];
  const float* kemb      = (const float*)d_in[8];
  const float* Wl        = (const float*)d_in[9];
  const float* Wr        = (const float*)d_in[10];
  const float* Wt        = (const float*)d_in[11];
  const float* bconv     = (const float*)d_in[12];
  const float* Wjm       = (const float*)d_in[13];
  float* out = (float*)d_out;
  char* wsb = (char*)d_ws;

  // workspace layout (~81 MB used; ws is 256 MiB; no overlays)
  float* hA    = (float*)(wsb + 0);          // 16.78 MB (ping)
  float* hB    = (float*)(wsb + 16777216);   // 16.78 MB (pong)
  float* feat  = (float*)(wsb + 33554432);   // 16.78 MB
  float* WT    = (float*)(wsb + 50331648);   // 13.11 MB
  float* delta = (float*)(wsb + 63438848);   // 6.55  MB
  float* gT    = (float*)(wsb + 69992448);   // 6.55  MB
  float* z     = (float*)(wsb + 76546048);   // 100 KB (squashed z)
  float* l2b   = (float*)(wsb + 76853248);   // 128 KB
  float* U     = (float*)(wsb + 76984320);   // 512 KB
  float* Vsum  = (float*)(wsb + 77508608);   // 512 KB
  float* mw    = (float*)(wsb + 78032896);   // 128 KB
  float* sw    = (float*)(wsb + 78163968);   // 128 KB
  float* SCT   = (float*)(wsb + 78295040);   // 512 KB
  float* zpart = (float*)(wsb + 78819328);   // 1.64 MB (800 x 512)

  k_init<<<5120, 256, 0, stream>>>(type_ids, token_ids, temb, kemb, hA, hB,
                                   Wjm, WT);

  for (int l = 0; l < NLAY; ++l) {
    const float* hp = (l & 1) ? hB : hA;
    float*       hn = (l & 1) ? hA : hB;
    k_conv<<<512, 256, 0, stream>>>(hp, hn, src, lw, rw,
                                    Wl + l * 16384, Wr + l * 16384, Wt + l * 16384,
                                    bconv + l * 128, feat + l * (M_INT * 128));
  }

  // after 4 layers: internal nodes live in hA; leaves in hA since embed
  k_l2<<<8192, 256, 0, stream>>>(hA, feat, l2b);
  k_topsel<<<32, 256, 0, stream>>>(l2b, hA, feat, U, Vsum);

  for (int it = 0; it < 3; ++it) {
    k_vtsA<<<512, 1024, 0, stream>>>(U, Vsum, mw, sw);
    k_vtsB<<<512, 1024, 0, stream>>>(U, Vsum, mw, sw, SCT, it == 2 ? 1 : 0);
  }

  for (int it = 0; it < 3; ++it) {
    k_zsweep<<<800, 256, 0, stream>>>(WT, SCT, gT, zpart, it == 0 ? 1 : 0);
    k_zred<<<100, 256, 0, stream>>>(zpart, z, out, it == 2 ? 1 : 0);
    if (it < 2)
      k_dsweep<<<1024, 256, 0, stream>>>(WT, SCT, z, delta, gT, it == 0 ? 1 : 0);
  }
}

// Round 12
// 431.206 us; speedup vs baseline: 6.6220x; 1.0024x over previous
//
#include <hip/hip_runtime.h>

// ---------------------------------------------------------------------------
// TreeCaps forward, MI355X fp32 implementation.
// Fixed forest: per graph of 1024 nodes, node p's children are 4p+1..4p+4;
// nodes 0..255 are internal (updated each layer), 256..1023 are leaves.
// R2: k_dsweep 1 block per node -> WT read exactly once.
// R4: occupancy attack -> WIN (523->476).
// R5: conv gather-fusion + K-loop dbuf -> NEUTRAL (477); fusion kept.
// R7: zsweep atomics eliminated (2-stage partial-sum) -> WIN (518->432).
// R8: VTS 256-thr reg-blocking -> REGRESSION (2 waves/SIMD cliff); reverted.
// R9/R13: best verified multi-kernel state: 432.2us.
// R10-R12: fused back half w/ software grid barriers -> all CORRECT, all
//     ~2400-2800us (~200us/barrier regardless of arrival scheme). Abandoned.
// R14: (this round) TLP lever on the two sub-knee kernels:
//   - k_conv: single-buffered Ws/AsT (R5 dbuf was neutral) -> LDS 69->34.5KB
//     -> 4 blocks/CU = 16 waves/CU (was 8). Same fma order -> bit-exact.
//   - k_zsweep: grid 800->1600 (32-n chunks) -> 25 waves/CU (was 12.5).
//     R6's untested half (R6's regression was the atomics, proven by
//     WRITE_SIZE); plain stores kept. k_zred sums 32 partials.
// ---------------------------------------------------------------------------

#define BG      32
#define NPG     1024
#define HH      128
#define NLAY    4
#define INT_PG  256
#define M_INT   8192      // BG*INT_PG
#define NN      32768     // BG*NPG
#define EPG     1023
#define DCC     16
#define NS      50

// ---- init: embed h0 (leaves to both bufs) + transpose Wjm -> WT -----------
__global__ void k_init(const int* __restrict__ tids, const int* __restrict__ kids,
                       const float* __restrict__ temb, const float* __restrict__ kemb,
                       float* __restrict__ hA, float* __restrict__ hB,
                       const float* __restrict__ Wjm, float* __restrict__ WT) {
  __shared__ float w[3200];
  int tid = threadIdx.x;
  if (blockIdx.x < 4096) {                         // ---- embed part
    int idx = blockIdx.x * 256 + tid;              // NN*32
    int n = idx >> 5, c4 = idx & 31;
    float4 v;
    if (c4 < 16) v = *(const float4*)(temb + tids[n] * 64 + c4 * 4);
    else         v = *(const float4*)(kemb + kids[n] * 64 + (c4 - 16) * 4);
    *(float4*)(hA + n * 128 + c4 * 4) = v;
    if ((n & 1023) >= INT_PG)                      // leaves constant in both bufs
      *(float4*)(hB + n * 128 + c4 * 4) = v;
  } else {                                         // ---- transW part
    int n = blockIdx.x - 4096;
    for (int i = tid; i < 3200; i += 256) w[i] = Wjm[n * 3200 + i];
    __syncthreads();
    for (int i = tid; i < 3200; i += 256) {
      int s = i >> 6, cm = i & 63;
      int cc = cm >> 2, m = cm & 3;
      WT[(s * 1024 + n) * 64 + cm] = w[(cc * NS + s) * 4 + m];
    }
  }
}

// --- fused gather+conv: new_h = relu(hl@Wl + hr@Wr + h@Wt + b) -------------
// [8192 rows, K=384, N=128]; block = 256 thr, 16 rows x 128 cols, 2x4/thread.
// R14: single-buffered Ws/AsT -> 34.5KB LDS -> 4 blocks/CU (16 waves/CU).
// Staging + fma order identical to R5 -> bit-exact.
__global__ __launch_bounds__(256) void k_conv(
    const float* __restrict__ hp, float* __restrict__ hn,
    const int* __restrict__ src, const float* __restrict__ lw,
    const float* __restrict__ rw,
    const float* __restrict__ Wl, const float* __restrict__ Wr,
    const float* __restrict__ Wt, const float* __restrict__ bias,
    float* __restrict__ feat) {
  __shared__ float Ws[32][128];    // 16 KB
  __shared__ float AsT[32][20];    // 2.5 KB, padded
  __shared__ float hlS[16][128];   // 8 KB
  __shared__ float hrS[16][128];   // 8 KB
  int tid = threadIdx.x;
  int tx = tid & 31, ty = tid >> 5;          // ty 0..7 -> rows 2*ty, 2*ty+1
  int rowBase = blockIdx.x * 16;
  int g = rowBase >> 8, plBase = rowBase & 255;
  int nodeBase = g * NPG + plBase;

  // ---- stage weighted child sums for 16 parents (k_gather fma order) ----
  #pragma unroll
  for (int t = 0; t < 2; ++t) {
    int it = t * 256 + tid;                  // 0..511
    int pw = it >> 5, c4 = it & 31;
    int pl = plBase + pw;
    float4 al = make_float4(0.f, 0.f, 0.f, 0.f);
    float4 ar = make_float4(0.f, 0.f, 0.f, 0.f);
    #pragma unroll
    for (int j = 0; j < 4; ++j) {
      int cc = 4 * pl + 1 + j;
      if (cc < NPG) {
        int e = g * EPG + cc - 1;
        int child = src[e];
        float lv = lw[e], rv = rw[e];
        float4 hv = *(const float4*)(hp + child * 128 + c4 * 4);
        al.x = fmaf(lv, hv.x, al.x); al.y = fmaf(lv, hv.y, al.y);
        al.z = fmaf(lv, hv.z, al.z); al.w = fmaf(lv, hv.w, al.w);
        ar.x = fmaf(rv, hv.x, ar.x); ar.y = fmaf(rv, hv.y, ar.y);
        ar.z = fmaf(rv, hv.z, ar.z); ar.w = fmaf(rv, hv.w, ar.w);
      }
    }
    *(float4*)&hlS[pw][c4 * 4] = al;
    *(float4*)&hrS[pw][c4 * 4] = ar;
  }
  __syncthreads();

  float acc[2][4] = {};
  int sr = tid >> 3, sc4 = (tid & 7) * 4;    // valid for tid<128: sr 0..15

  for (int kc = 0; kc < 12; ++kc) {
    int ssel = kc >> 2, kcol = (kc & 3) * 32;
    float4 av = make_float4(0.f, 0.f, 0.f, 0.f);
    if (tid < 128) {
      if (ssel == 0)      av = *(const float4*)&hlS[sr][kcol + sc4];
      else if (ssel == 1) av = *(const float4*)&hrS[sr][kcol + sc4];
      else                av = *(const float4*)(hp + (nodeBase + sr) * 128 + kcol + sc4);
    }
    const float* wsrc = ((ssel == 0) ? Wl : (ssel == 1) ? Wr : Wt) + kcol * 128;
    float4 wv0, wv1, wv2, wv3;
    {
      int f0 = tid, f1 = tid + 256, f2 = tid + 512, f3 = tid + 768;
      wv0 = *(const float4*)(wsrc + (f0 >> 5) * 128 + (f0 & 31) * 4);
      wv1 = *(const float4*)(wsrc + (f1 >> 5) * 128 + (f1 & 31) * 4);
      wv2 = *(const float4*)(wsrc + (f2 >> 5) * 128 + (f2 & 31) * 4);
      wv3 = *(const float4*)(wsrc + (f3 >> 5) * 128 + (f3 & 31) * 4);
    }
    __syncthreads();                         // prev FMA reads done
    if (tid < 128) {
      AsT[sc4 + 0][sr] = av.x; AsT[sc4 + 1][sr] = av.y;
      AsT[sc4 + 2][sr] = av.z; AsT[sc4 + 3][sr] = av.w;
    }
    {
      int f0 = tid, f1 = tid + 256, f2 = tid + 512, f3 = tid + 768;
      *(float4*)&Ws[f0 >> 5][(f0 & 31) * 4] = wv0;
      *(float4*)&Ws[f1 >> 5][(f1 & 31) * 4] = wv1;
      *(float4*)&Ws[f2 >> 5][(f2 & 31) * 4] = wv2;
      *(float4*)&Ws[f3 >> 5][(f3 & 31) * 4] = wv3;
    }
    __syncthreads();
    #pragma unroll
    for (int kk = 0; kk < 32; ++kk) {
      float4 wv = *(float4*)&Ws[kk][tx * 4];
      float2 av2 = *(float2*)&AsT[kk][ty * 2];
      float aa[2] = {av2.x, av2.y};
      float ww[4] = {wv.x, wv.y, wv.z, wv.w};
      #pragma unroll
      for (int i = 0; i < 2; ++i)
        #pragma unroll
        for (int j = 0; j < 4; ++j)
          acc[i][j] = fmaf(aa[i], ww[j], acc[i][j]);
    }
  }
  float4 bv = *(const float4*)(bias + tx * 4);
  float bb[4] = {bv.x, bv.y, bv.z, bv.w};
  #pragma unroll
  for (int i = 0; i < 2; ++i) {
    int r = ty * 2 + i;
    float4 o = make_float4(fmaxf(acc[i][0] + bb[0], 0.f),
                           fmaxf(acc[i][1] + bb[1], 0.f),
                           fmaxf(acc[i][2] + bb[2], 0.f),
                           fmaxf(acc[i][3] + bb[3], 0.f));
    *(float4*)(feat + (rowBase + r) * 128 + tx * 4) = o;
    *(float4*)(hn + (nodeBase + r) * 128 + tx * 4) = o;
  }
}

// ---------------- l2 norms over [H, L] per node ----------------------------
__global__ void k_l2(const float* __restrict__ h, const float* __restrict__ feat,
                     float* __restrict__ l2) {
  int wid = (blockIdx.x * 256 + threadIdx.x) >> 6;   // node id
  int lane = threadIdx.x & 63;
  int g = wid >> 10, local = wid & 1023;
  float s = 0.f;
  if (local >= INT_PG) {                              // leaf: 4*||h0||^2
    const float* p = h + wid * 128;
    float a = p[lane], b = p[lane + 64];
    s = (a * a + b * b) * 4.f;
  } else {
    int row = (g * INT_PG + local) * 128;
    #pragma unroll
    for (int l = 0; l < 4; ++l) {
      const float* p = feat + l * (M_INT * 128) + row;
      float a = p[lane], b = p[lane + 64];
      s += a * a + b * b;
    }
  }
  #pragma unroll
  for (int off = 32; off; off >>= 1) s += __shfl_down(s, off);
  if (lane == 0) l2[wid] = s;
}

// ------ fused top-8 + buildU: one block per graph --------------------------
__global__ __launch_bounds__(256) void k_topsel(const float* __restrict__ l2,
                                                const float* __restrict__ h,
                                                const float* __restrict__ feat,
                                                float* __restrict__ U,
                                                float* __restrict__ Vsum) {
  __shared__ int ssel[8];
  int g = blockIdx.x, tid = threadIdx.x;
  int lane = tid & 63;
  if (tid < 64) {
    unsigned long long kk[16];
    #pragma unroll
    for (int k = 0; k < 16; ++k) {
      int i = k * 64 + lane;
      unsigned vb = __float_as_uint(l2[g * 1024 + i]);  // l2 >= 0: uint order ok
      kk[k] = ((unsigned long long)vb << 32) | (unsigned)(~i);
    }
    for (int r = 0; r < 8; ++r) {
      unsigned long long best = 0ULL;
      #pragma unroll
      for (int k = 0; k < 16; ++k) best = (kk[k] > best) ? kk[k] : best;
      #pragma unroll
      for (int off = 32; off; off >>= 1) {
        unsigned long long o = __shfl_down(best, off);
        best = (o > best) ? o : best;
      }
      best = __shfl(best, 0);
      if (lane == 0) ssel[r] = (int)(~(unsigned)(best & 0xffffffffu));
      #pragma unroll
      for (int k = 0; k < 16; ++k) if (kk[k] == best) kk[k] = 0ULL;
    }
  }
  __syncthreads();
  for (int t = 0; t < 4; ++t) {
    int idx = t * 256 + tid;                  // 0..1023
    int rank = idx >> 7, hh = idx & 127;
    int local = ssel[rank];
    float4 v;
    if (local >= INT_PG) {
      float x = h[(g * NPG + local) * 128 + hh];
      v = make_float4(x, x, x, x);
    } else {
      int row = (g * INT_PG + local) * 128 + hh;
      v.x = feat[row];
      v.y = feat[M_INT * 128 + row];
      v.z = feat[2 * M_INT * 128 + row];
      v.w = feat[3 * M_INT * 128 + row];
    }
    int o = g * 1024 + rank * 128 + hh;
    ((float4*)U)[o] = v;
    ((float4*)Vsum)[o] = v;
  }
}

// ------------- VTS phase A: per-row softmax stats of alpha = U@Vsum.T ------
// 1024-thr (32 waves/CU). p = tid&15 (j-chunk of 64), r = tid>>4;
// shfl_xor(8,4,2,1) = old LDS-tree pairing, bit-exact.
__global__ __launch_bounds__(1024) void k_vtsA(const float* __restrict__ U,
                                               const float* __restrict__ Vsum,
                                               float* __restrict__ mw, float* __restrict__ sw) {
  __shared__ float4 Vs2[64 * 17];   // 17.4 KB; elem j=p*64+i at [i*17+p]
  int g = blockIdx.x >> 4, rb = (blockIdx.x & 15) * 64;
  int tid = threadIdx.x, p = tid & 15, r = tid >> 4;
  Vs2[(tid & 63) * 17 + (tid >> 6)] = ((const float4*)Vsum)[g * 1024 + tid];
  __syncthreads();
  float4 u = ((const float4*)U)[g * 1024 + rb + r];
  float m = -3.4e38f;
  for (int i = 0; i < 64; ++i) {
    float4 v = Vs2[i * 17 + p];
    float a = u.x * v.x + u.y * v.y + u.z * v.z + u.w * v.w;
    m = fmaxf(m, a);
  }
  #pragma unroll
  for (int mk = 8; mk; mk >>= 1) m = fmaxf(m, __shfl_xor(m, mk));
  float s = 0.f;
  for (int i = 0; i < 64; ++i) {
    float4 v = Vs2[i * 17 + p];
    float a = u.x * v.x + u.y * v.y + u.z * v.z + u.w * v.w;
    s += __expf(a - m);
  }
  #pragma unroll
  for (int mk = 8; mk; mk >>= 1) s += __shfl_xor(s, mk);
  if (p == 0) {
    mw[g * 1024 + rb + r] = m;
    sw[g * 1024 + rb + r] = s;
  }
}

// ------------- VTS phase B: Vnew = beta.T @ U; update Vsum or emit SC ------
__global__ __launch_bounds__(1024) void k_vtsB(const float* __restrict__ U,
                                               float* __restrict__ Vsum,
                                               const float* __restrict__ mw,
                                               const float* __restrict__ sw,
                                               float* __restrict__ SCT, int last) {
  __shared__ float4 Us2[64 * 17];   // 17.4 KB; row i of chunk p at [i*17+p]
  __shared__ float2 Ms2[64 * 17];   // 8.7 KB  (m, 1/s)
  int g = blockIdx.x >> 4, cb = (blockIdx.x & 15) * 64;
  int tid = threadIdx.x, p = tid & 15, q = tid >> 4;
  Us2[(tid & 63) * 17 + (tid >> 6)] = ((const float4*)U)[g * 1024 + tid];
  Ms2[(tid & 63) * 17 + (tid >> 6)] =
      make_float2(mw[g * 1024 + tid], 1.0f / sw[g * 1024 + tid]);
  __syncthreads();
  float4 v = ((const float4*)Vsum)[g * 1024 + cb + q];
  float4 acc = make_float4(0.f, 0.f, 0.f, 0.f);
  for (int i = 0; i < 64; ++i) {
    float4 uu = Us2[i * 17 + p];
    float2 st = Ms2[i * 17 + p];
    float a = uu.x * v.x + uu.y * v.y + uu.z * v.z + uu.w * v.w;
    float w = __expf(a - st.x) * st.y;
    acc.x = fmaf(w, uu.x, acc.x); acc.y = fmaf(w, uu.y, acc.y);
    acc.z = fmaf(w, uu.z, acc.z); acc.w = fmaf(w, uu.w, acc.w);
  }
  #pragma unroll
  for (int mk = 8; mk; mk >>= 1) {
    acc.x += __shfl_xor(acc.x, mk);
    acc.y += __shfl_xor(acc.y, mk);
    acc.z += __shfl_xor(acc.z, mk);
    acc.w += __shfl_xor(acc.w, mk);
  }
  if (p == 0) {
    float4 o = acc;
    int jc = cb + q;
    if (last) {
      float sq = o.x * o.x + o.y * o.y + o.z * o.z + o.w * o.w;
      float f = (sq / (1.f + sq)) / (sqrtf(sq + 1e-10f) + 1e-8f);
      ((float4*)SCT)[jc * 32 + g] = make_float4(o.x * f, o.y * f, o.z * f, o.w * f);
    } else {
      float4 w0 = ((const float4*)Vsum)[g * 1024 + jc];
      ((float4*)Vsum)[g * 1024 + jc] = make_float4(w0.x + o.x, w0.y + o.y,
                                                   w0.z + o.z, w0.w + o.w);
    }
  }
}

// ------------- Z sweep stage 1: partial sums, NO atomics -------------------
// R14: grid 1600 = 50 sb x 32 nb, 32 n each (25 waves/CU, was 12.5).
__global__ __launch_bounds__(256) void k_zsweep(const float* __restrict__ WT,
                                                const float* __restrict__ SCT,
                                                const float* __restrict__ gT,
                                                float* __restrict__ zpart, int it0) {
  int sb = blockIdx.x >> 5, nb = blockIdx.x & 31;
  int tid = threadIdx.x;
  int b = tid & 31, ch = tid >> 5;             // ch in 0..7: c = ch, ch+8
  int n0 = nb * 32;
  const float4* wt = (const float4*)WT + (sb * 1024 + n0) * 16;
  const float4* sct = (const float4*)SCT + n0 * 32 + b;
  const float* gp = gT + (sb * 1024 + n0) * 32 + b;
  float a0 = 0.f, a1 = 0.f;
  #pragma unroll 8
  for (int nn = 0; nn < 32; ++nn) {
    float4 w0 = wt[nn * 16 + ch];
    float4 w1 = wt[nn * 16 + ch + 8];
    float4 s4 = sct[nn * 32];
    float gm = it0 ? (1.0f / 50.0f) : gp[nn * 32];
    float t0 = w0.x * s4.x + w0.y * s4.y + w0.z * s4.z + w0.w * s4.w;
    float t1 = w1.x * s4.x + w1.y * s4.y + w1.z * s4.z + w1.w * s4.w;
    a0 = fmaf(gm, t0, a0);
    a1 = fmaf(gm, t1, a1);
  }
  zpart[blockIdx.x * 512 + tid] = a0;
  zpart[blockIdx.x * 512 + 256 + tid] = a1;
}

// ---- Z sweep stage 2: sum 32 partials + squash -> z; last iter: logits ----
__global__ void k_zred(const float* __restrict__ zpart, float* __restrict__ z,
                       float* __restrict__ out, int last) {
  __shared__ float sb_[256];
  __shared__ float fb[16];
  __shared__ float sqb[16];
  int tid = threadIdx.x;
  int idx = blockIdx.x * 256 + tid;            // 25600 = (b*NS+sb)*16+c
  int c = idx & 15;
  int sbk = (idx >> 4) % NS;
  int b = idx / (16 * NS);
  int lofs = (c < 8) ? (c * 32 + b) : (256 + (c - 8) * 32 + b);
  const float* zp = zpart + sbk * 32 * 512 + lofs;
  float s = 0.f;
  #pragma unroll
  for (int nb = 0; nb < 32; ++nb) s += zp[nb * 512];
  sb_[tid] = s;
  __syncthreads();
  if ((tid & 15) == 0) {                       // one lane per (b,s) pair
    float sq = 0.f;
    #pragma unroll
    for (int cc = 0; cc < 16; ++cc) sq += sb_[tid + cc] * sb_[tid + cc];
    float f = (sq / (1.f + sq)) / (sqrtf(sq + 1e-10f) + 1e-8f);
    fb[tid >> 4] = f;
    sqb[tid >> 4] = sq;
  }
  __syncthreads();
  z[idx] = s * fb[tid >> 4];
  if (last && (tid & 15) == 0) {
    float sq = sqb[tid >> 4], f = fb[tid >> 4];
    float lg = sqrtf(sq * f * f + 1e-10f);
    int pr = idx >> 4;                         // b*NS + s
    out[pr] = lg;
    out[pr + 1600] = lg;
  }
}

// -- D sweep + gamma: dtot = delta_old + <v,z>; gT = softmax_s(dtot) --------
__global__ __launch_bounds__(256) void k_dsweep(const float* __restrict__ WT,
                                                const float* __restrict__ SCT,
                                                const float* __restrict__ z,
                                                float* __restrict__ delta,
                                                float* __restrict__ gT, int first) {
  __shared__ float wl[50 * 64];     // [s][c][m]  12.8 KB
  __shared__ float4 scl[32];        // SCT[n][b][:]
  __shared__ float dtot[NS][32];    // 6.4 KB
  __shared__ float mb[32], ib[32];
  int n = blockIdx.x;
  int tid = threadIdx.x;
  for (int i = tid; i < 3200; i += 256)
    wl[i] = WT[((i >> 6) * 1024 + n) * 64 + (i & 63)];
  if (tid < 32) scl[tid] = ((const float4*)SCT)[n * 32 + tid];
  __syncthreads();
  for (int idx = tid; idx < 1600; idx += 256) {
    int s = idx >> 5, b = idx & 31;              // lanes 0-31: same s (LDS bcast)
    const float4* wp = (const float4*)(wl + s * 64);
    const float4* zp = (const float4*)(z + (b * 50 + s) * 16);
    float4 z0 = zp[0], z1 = zp[1], z2 = zp[2], z3 = zp[3];
    float zs[16] = {z0.x, z0.y, z0.z, z0.w, z1.x, z1.y, z1.z, z1.w,
                    z2.x, z2.y, z2.z, z2.w, z3.x, z3.y, z3.z, z3.w};
    float4 y = make_float4(0.f, 0.f, 0.f, 0.f);
    #pragma unroll
    for (int c = 0; c < 16; ++c) {
      float4 w = wp[c];
      float zc = zs[c];
      y.x = fmaf(zc, w.x, y.x); y.y = fmaf(zc, w.y, y.y);
      y.z = fmaf(zc, w.z, y.z); y.w = fmaf(zc, w.w, y.w);
    }
    float4 sc = scl[b];
    float dd = sc.x * y.x + sc.y * y.y + sc.z * y.z + sc.w * y.w;
    float dt = first ? dd : (delta[(s * 1024 + n) * 32 + b] + dd);
    dtot[s][b] = dt;
    if (first) delta[(s * 1024 + n) * 32 + b] = dt;  // needed by next dsweep
  }
  __syncthreads();
  if (tid < 32) {                                    // softmax stats over s
    float m = -3.4e38f;
    for (int s = 0; s < NS; ++s) m = fmaxf(m, dtot[s][tid]);
    float sum = 0.f;
    for (int s = 0; s < NS; ++s) sum += __expf(dtot[s][tid] - m);
    mb[tid] = m; ib[tid] = 1.0f / sum;
  }
  __syncthreads();
  for (int idx = tid; idx < 1600; idx += 256) {
    int s = idx >> 5, b = idx & 31;
    gT[(s * 1024 + n) * 32 + b] = __expf(dtot[s][b] - mb[b]) * ib[b];
  }
}

// ---------------------------------------------------------------------------
extern "C" void kernel_launch(void* const* d_in, const int* in_sizes, int n_in,
                              void* d_out, int out_size, void* d_ws, size_t ws_size,
                              hipStream_t stream) {
  const int*   type_ids  = (const int*)d_in[0];
  const int*   token_ids = (const int*)d_in[1];
  const int*   src       = (const int*)d_in[2];
  const float* lw        = (const float*)d_in[4];
  const float* rw        = (const float*)d_in[5];
  const float* temb      = (const float*)d_in[7];
  const float* kemb      = (const float*)d_in[8];
  const float* Wl        = (const float*)d_in[9];
  const float* Wr        = (const float*)d_in[10];
  const float* Wt        = (const float*)d_in[11];
  const float* bconv     = (const float*)d_in[12];
  const float* Wjm       = (const float*)d_in[13];
  float* out = (float*)d_out;
  char* wsb = (char*)d_ws;

  // workspace layout (~84 MB used; ws is 256 MiB; no overlays)
  float* hA    = (float*)(wsb + 0);          // 16.78 MB (ping)
  float* hB    = (float*)(wsb + 16777216);   // 16.78 MB (pong)
  float* feat  = (float*)(wsb + 33554432);   // 16.78 MB
  float* WT    = (float*)(wsb + 50331648);   // 13.11 MB
  float* delta = (float*)(wsb + 63438848);   // 6.55  MB
  float* gT    = (float*)(wsb + 69992448);   // 6.55  MB
  float* z     = (float*)(wsb + 76546048);   // 100 KB (squashed z)
  float* l2b   = (float*)(wsb + 76853248);   // 128 KB
  float* U     = (float*)(wsb + 76984320);   // 512 KB
  float* Vsum  = (float*)(wsb + 77508608);   // 512 KB
  float* mw    = (float*)(wsb + 78032896);   // 128 KB
  float* sw    = (float*)(wsb + 78163968);   // 128 KB
  float* SCT   = (float*)(wsb + 78295040);   // 512 KB
  float* zpart = (float*)(wsb + 78819328);   // 3.28 MB (1600 x 512)

  k_init<<<5120, 256, 0, stream>>>(type_ids, token_ids, temb, kemb, hA, hB,
                                   Wjm, WT);

  for (int l = 0; l < NLAY; ++l) {
    const float* hp = (l & 1) ? hB : hA;
    float*       hn = (l & 1) ? hA : hB;
    k_conv<<<512, 256, 0, stream>>>(hp, hn, src, lw, rw,
                                    Wl + l * 16384, Wr + l * 16384, Wt + l * 16384,
                                    bconv + l * 128, feat + l * (M_INT * 128));
  }

  // after 4 layers: internal nodes live in hA; leaves in hA since embed
  k_l2<<<8192, 256, 0, stream>>>(hA, feat, l2b);
  k_topsel<<<32, 256, 0, stream>>>(l2b, hA, feat, U, Vsum);

  for (int it = 0; it < 3; ++it) {
    k_vtsA<<<512, 1024, 0, stream>>>(U, Vsum, mw, sw);
    k_vtsB<<<512, 1024, 0, stream>>>(U, Vsum, mw, sw, SCT, it == 2 ? 1 : 0);
  }

  for (int it = 0; it < 3; ++it) {
    k_zsweep<<<1600, 256, 0, stream>>>(WT, SCT, gT, zpart, it == 0 ? 1 : 0);
    k_zred<<<100, 256, 0, stream>>>(zpart, z, out, it == 2 ? 1 : 0);
    if (it < 2)
      k_dsweep<<<1024, 256, 0, stream>>>(WT, SCT, z, delta, gT, it == 0 ? 1 : 0);
  }
}